// Round 1
// baseline (524.087 us; speedup 1.0000x reference)
//
#include <hip/hip_runtime.h>
#include <stdint.h>

typedef unsigned short u16;
typedef __bf16 bf16x8 __attribute__((ext_vector_type(8)));
typedef float    f32x4 __attribute__((ext_vector_type(4)));
typedef unsigned short u16x8 __attribute__((ext_vector_type(8)));

#define BB 8
#define SS 1024
#define EE 2048
#define HH 16
#define DD 128

__device__ __forceinline__ u16 f2bf(float f){
  union { float f; unsigned u; } v; v.f = f;
  unsigned r = v.u + 0x7FFFu + ((v.u >> 16) & 1u);
  return (u16)(r >> 16);
}
__device__ __forceinline__ float bf2f(u16 h){
  union { unsigned u; float f; } v; v.u = ((unsigned)h) << 16;
  return v.f;
}
__device__ __forceinline__ bf16x8 ld8(const u16* p){
  return __builtin_bit_cast(bf16x8, *(const u16x8*)p);
}

// ---------------- f32 -> bf16 convert (vectorized) ----------------
__global__ __launch_bounds__(256) void cvt_f32_bf16(const float* __restrict__ in,
                                                    u16* __restrict__ out, int n){
  int i = (blockIdx.x*256 + threadIdx.x)*8;
  if (i >= n) return;
  float4 v0 = *(const float4*)(in + i);
  float4 v1 = *(const float4*)(in + i + 4);
  u16x8 o;
  o[0]=f2bf(v0.x); o[1]=f2bf(v0.y); o[2]=f2bf(v0.z); o[3]=f2bf(v0.w);
  o[4]=f2bf(v1.x); o[5]=f2bf(v1.y); o[6]=f2bf(v1.z); o[7]=f2bf(v1.w);
  *(u16x8*)(out + i) = o;
}

// ---------------- W (KxN f32) -> Wt (NxK bf16), LDS-tiled ----------------
__global__ __launch_bounds__(256) void transposeW(const float* __restrict__ W,
                                                  u16* __restrict__ Wt, int K, int N){
  __shared__ float t[32][33];
  int c = threadIdx.x & 31, r = threadIdx.x >> 5; // r in 0..7
  int bx = blockIdx.x, by = blockIdx.y;           // bx along N, by along K
  #pragma unroll
  for (int i = 0; i < 32; i += 8)
    t[r+i][c] = W[(size_t)(by*32 + r + i)*N + bx*32 + c];
  __syncthreads();
  #pragma unroll
  for (int i = 0; i < 32; i += 8)
    Wt[(size_t)(bx*32 + r + i)*K + by*32 + c] = f2bf(t[c][r+i]);
}

// ---------------- RoPE tables: cos/sin[s][j], j=0..47 ----------------
__global__ __launch_bounds__(256) void rope_tables(float* __restrict__ cosb,
                                                   float* __restrict__ sinb){
  int i = blockIdx.x*256 + threadIdx.x;
  if (i >= SS*48) return;
  int s = i / 48, j = i % 48;
  float freq = powf(10000.0f, -((float)(2*j)) / 96.0f);
  float e = (float)s * freq;
  cosb[i] = cosf(e);
  sinb[i] = sinf(e);
}

// ---------------- RoPE apply in-place on [B*S][E] bf16, per (row,head) ----------------
__global__ __launch_bounds__(256) void rope_apply(u16* __restrict__ buf,
                                                  const float* __restrict__ cosb,
                                                  const float* __restrict__ sinb){
  int t = blockIdx.x*256 + threadIdx.x;   // B*S*H = 131072 threads
  int row = t >> 4, h = t & 15, s = row & (SS-1);
  u16* p = buf + (size_t)row*EE + h*DD + 32;  // 96-wide rope region
  float e[48], o[48];
  #pragma unroll
  for (int c = 0; c < 12; c++){
    u16x8 v = *(const u16x8*)(p + c*8);
    #pragma unroll
    for (int j = 0; j < 4; j++){
      e[c*4 + j] = bf2f(v[2*j]);
      o[c*4 + j] = bf2f(v[2*j+1]);
    }
  }
  #pragma unroll
  for (int j = 0; j < 48; j++){
    float cs = cosb[s*48 + j], sn = sinb[s*48 + j];
    p[j]      = f2bf(e[j]*cs - o[j]*sn);
    p[48 + j] = f2bf(o[j]*cs + e[j]*sn);
  }
}

// ---------------- GEMM: C[MxN] = A[MxK] * Bt[NxK]^T, all bf16, f32 acc ----------------
#define LDK 40  // padded LDS row stride (elements); 40*2=80B, 16B aligned, conflict-free reads

__global__ __launch_bounds__(256) void gemm_bt(const u16* __restrict__ A,
    const u16* __restrict__ Bt, u16* __restrict__ C, int M, int N, int K){
  __shared__ u16 Al[128*LDK];
  __shared__ u16 Bl[128*LDK];
  const int tid = threadIdx.x;
  const int lane = tid & 63, w = tid >> 6;
  const int wr = w >> 1, wc = w & 1;
  const int l15 = lane & 15, l4 = lane >> 4;
  const int bm = blockIdx.y*128, bn = blockIdx.x*128;
  const int srow = tid >> 2;        // 0..63
  const int skc  = (tid & 3) * 8;   // 0,8,16,24
  f32x4 acc[4][4] = {};
  for (int k0 = 0; k0 < K; k0 += 32){
    u16x8 a0 = *(const u16x8*)(A  + (size_t)(bm + srow     )*K + k0 + skc);
    u16x8 a1 = *(const u16x8*)(A  + (size_t)(bm + srow + 64)*K + k0 + skc);
    u16x8 b0 = *(const u16x8*)(Bt + (size_t)(bn + srow     )*K + k0 + skc);
    u16x8 b1 = *(const u16x8*)(Bt + (size_t)(bn + srow + 64)*K + k0 + skc);
    __syncthreads();
    *(u16x8*)(Al + srow*LDK + skc)      = a0;
    *(u16x8*)(Al + (srow+64)*LDK + skc) = a1;
    *(u16x8*)(Bl + srow*LDK + skc)      = b0;
    *(u16x8*)(Bl + (srow+64)*LDK + skc) = b1;
    __syncthreads();
    bf16x8 af[4], bfr[4];
    #pragma unroll
    for (int m = 0; m < 4; m++) af[m]  = ld8(Al + (wr*64 + m*16 + l15)*LDK + l4*8);
    #pragma unroll
    for (int n = 0; n < 4; n++) bfr[n] = ld8(Bl + (wc*64 + n*16 + l15)*LDK + l4*8);
    #pragma unroll
    for (int m = 0; m < 4; m++)
      #pragma unroll
      for (int n = 0; n < 4; n++)
        acc[m][n] = __builtin_amdgcn_mfma_f32_16x16x32_bf16(af[m], bfr[n], acc[m][n], 0, 0, 0);
  }
  #pragma unroll
  for (int m = 0; m < 4; m++)
    #pragma unroll
    for (int n = 0; n < 4; n++)
      #pragma unroll
      for (int r = 0; r < 4; r++){
        int row = bm + wr*64 + m*16 + l4*4 + r;
        int col = bn + wc*64 + n*16 + l15;
        C[(size_t)row*N + col] = f2bf(acc[m][n][r]);
      }
}

// ---------------- Flash attention, causal, 4 waves x 16 q-rows, KV tile 64 ----------------
#define KLD 136  // K_lds row stride (elements): 272B -> 2-way-free b128 reads

__global__ __launch_bounds__(256) void attn(const u16* __restrict__ qp,
                                            const u16* __restrict__ kp,
                                            const u16* __restrict__ vp,
                                            float* __restrict__ out){
  __shared__ u16 Kl[64*KLD];      // 17408 B
  __shared__ u16 Vt[128*64];      // 16384 B, transposed + XOR chunk swizzle
  __shared__ u16 Pl[4][16*72];    // 9216 B, wave-private P staging
  const int tid = threadIdx.x, lane = tid & 63, w = tid >> 6;
  const int l15 = lane & 15, l4 = lane >> 4;
  const int qt = blockIdx.x, bh = blockIdx.y;
  const int b = bh >> 4, h = bh & 15;
  const int qbase = qt*64;
  const int srow = tid >> 4, sseg = tid & 15;
  const float scale = 0.08838834764831845f;   // 1/sqrt(128)

  // Q fragments in registers (16 rows per wave)
  const size_t rowq = (size_t)(b*SS + qbase + w*16 + l15)*EE + h*DD;
  bf16x8 qf[4];
  #pragma unroll
  for (int kk = 0; kk < 4; kk++) qf[kk] = ld8(qp + rowq + kk*32 + l4*8);

  f32x4 ao[8] = {};
  float mi[4], li[4];
  #pragma unroll
  for (int r = 0; r < 4; r++){ mi[r] = -1e30f; li[r] = 0.0f; }

  for (int kv0 = 0; kv0 <= qbase; kv0 += 64){
    __syncthreads();   // previous iteration's readers done
    // stage K (row-major, padded) and V (transposed, swizzled)
    #pragma unroll
    for (int p2 = 0; p2 < 4; p2++){
      int row = p2*16 + srow;
      size_t gsrc = (size_t)(b*SS + kv0 + row)*EE + h*DD + sseg*8;
      u16x8 kvv = *(const u16x8*)(kp + gsrc);
      *(u16x8*)(Kl + row*KLD + sseg*8) = kvv;
      u16x8 vv = *(const u16x8*)(vp + gsrc);
      #pragma unroll
      for (int j = 0; j < 8; j++){
        int d = sseg*8 + j;
        int chunk = ((row >> 3) ^ (d & 7) ^ ((d >> 3) & 7)) & 7;
        Vt[d*64 + chunk*8 + (row & 7)] = vv[j];
      }
    }
    __syncthreads();

    // QK^T: 4 n-tiles of 16 kv cols
    float sv[4][4];
    #pragma unroll
    for (int nt = 0; nt < 4; nt++){
      f32x4 sacc = {};
      #pragma unroll
      for (int kk = 0; kk < 4; kk++){
        bf16x8 kf = ld8(Kl + (nt*16 + l15)*KLD + kk*32 + l4*8);
        sacc = __builtin_amdgcn_mfma_f32_16x16x32_bf16(qf[kk], kf, sacc, 0, 0, 0);
      }
      #pragma unroll
      for (int r = 0; r < 4; r++){
        int qg = qbase + w*16 + l4*4 + r;
        int kg = kv0 + nt*16 + l15;
        sv[nt][r] = (kg <= qg) ? sacc[r]*scale : -1e30f;
      }
    }

    // online softmax per q-row (rows live in 16-lane groups)
    float pout[4][4];
    #pragma unroll
    for (int r = 0; r < 4; r++){
      float mx = fmaxf(fmaxf(sv[0][r], sv[1][r]), fmaxf(sv[2][r], sv[3][r]));
      #pragma unroll
      for (int off = 1; off < 16; off <<= 1) mx = fmaxf(mx, __shfl_xor(mx, off));
      float mnew = fmaxf(mi[r], mx);
      float alpha = expf(mi[r] - mnew);
      float rs = 0.0f;
      #pragma unroll
      for (int nt = 0; nt < 4; nt++){
        float pv = expf(sv[nt][r] - mnew);
        pout[nt][r] = pv; rs += pv;
      }
      #pragma unroll
      for (int off = 1; off < 16; off <<= 1) rs += __shfl_xor(rs, off);
      li[r] = li[r]*alpha + rs;
      mi[r] = mnew;
      #pragma unroll
      for (int n8 = 0; n8 < 8; n8++) ao[n8][r] *= alpha;
    }

    // P -> wave-private LDS (bf16), then PV
    #pragma unroll
    for (int nt = 0; nt < 4; nt++)
      #pragma unroll
      for (int r = 0; r < 4; r++)
        Pl[w][(l4*4 + r)*72 + nt*16 + l15] = f2bf(pout[nt][r]);

    #pragma unroll
    for (int kk = 0; kk < 2; kk++){
      bf16x8 pa = ld8(&Pl[w][l15*72 + kk*32 + l4*8]);
      #pragma unroll
      for (int n8 = 0; n8 < 8; n8++){
        int d = n8*16 + l15;
        int kvc = kk*4 + l4;  // (kk*32 + l4*8) >> 3
        int chunk = (kvc ^ (d & 7) ^ ((d >> 3) & 7)) & 7;
        bf16x8 vf = ld8(Vt + d*64 + chunk*8);
        ao[n8] = __builtin_amdgcn_mfma_f32_16x16x32_bf16(pa, vf, ao[n8], 0, 0, 0);
      }
    }
  }

  // epilogue: out[b][s][h*128+d] f32
  #pragma unroll
  for (int r = 0; r < 4; r++){
    float inv = 1.0f / li[r];
    size_t orow = (size_t)(b*SS + qbase + w*16 + l4*4 + r)*EE + h*DD;
    #pragma unroll
    for (int n8 = 0; n8 < 8; n8++)
      out[orow + n8*16 + l15] = ao[n8][r]*inv;
  }
}

// ---------------- launch ----------------
extern "C" void kernel_launch(void* const* d_in, const int* in_sizes, int n_in,
                              void* d_out, int out_size, void* d_ws, size_t ws_size,
                              hipStream_t stream){
  const float* x    = (const float*)d_in[0];
  const float* Wq   = (const float*)d_in[1];
  const float* Wkvd = (const float*)d_in[2];
  const float* Wku  = (const float*)d_in[3];
  const float* Wvu  = (const float*)d_in[4];
  float* out = (float*)d_out;
  char* ws = (char*)d_ws;

  u16*   xb    = (u16*)  (ws);                 // 33,554,432 B
  u16*   WqT   = (u16*)  (ws +  33554432);     //  8,388,608
  u16*   WkvdT = (u16*)  (ws +  41943040);     //  2,097,152
  u16*   WkuT  = (u16*)  (ws +  44040192);     //  2,097,152
  u16*   WvuT  = (u16*)  (ws +  46137344);     //  2,097,152
  float* cosb  = (float*)(ws +  48234496);     //    196,608
  float* sinb  = (float*)(ws +  48431104);     //    196,608
  u16*   qp    = (u16*)  (ws +  48627712);     // 33,554,432
  u16*   ckv   = (u16*)  (ws +  82182144);     //  8,388,608
  u16*   kp    = (u16*)  (ws +  90570752);     // 33,554,432
  u16*   vp    = (u16*)  (ws + 124125184);     // 33,554,432  (end 157,679,616)

  cvt_f32_bf16<<<(BB*SS*EE)/(256*8), 256, 0, stream>>>(x, xb, BB*SS*EE);
  transposeW<<<dim3(EE/32,  EE/32), 256, 0, stream>>>(Wq,   WqT,   EE,  EE);
  transposeW<<<dim3(512/32, EE/32), 256, 0, stream>>>(Wkvd, WkvdT, EE,  512);
  transposeW<<<dim3(EE/32, 512/32), 256, 0, stream>>>(Wku,  WkuT,  512, EE);
  transposeW<<<dim3(EE/32, 512/32), 256, 0, stream>>>(Wvu,  WvuT,  512, EE);
  rope_tables<<<(SS*48 + 255)/256, 256, 0, stream>>>(cosb, sinb);

  gemm_bt<<<dim3(EE/128,  (BB*SS)/128), 256, 0, stream>>>(xb,  WqT,   qp,  BB*SS, EE,  EE);
  gemm_bt<<<dim3(512/128, (BB*SS)/128), 256, 0, stream>>>(xb,  WkvdT, ckv, BB*SS, 512, EE);
  gemm_bt<<<dim3(EE/128,  (BB*SS)/128), 256, 0, stream>>>(ckv, WkuT,  kp,  BB*SS, EE,  512);
  gemm_bt<<<dim3(EE/128,  (BB*SS)/128), 256, 0, stream>>>(ckv, WvuT,  vp,  BB*SS, EE,  512);

  rope_apply<<<(BB*SS*HH)/256, 256, 0, stream>>>(qp, cosb, sinb);
  rope_apply<<<(BB*SS*HH)/256, 256, 0, stream>>>(kp, cosb, sinb);

  attn<<<dim3(SS/64, BB*HH), 256, 0, stream>>>(qp, kp, vp, out);
}

// Round 2
// 392.209 us; speedup vs baseline: 1.3362x; 1.3362x over previous
//
#include <hip/hip_runtime.h>
#include <stdint.h>

typedef unsigned short u16;
typedef __bf16 bf16x8 __attribute__((ext_vector_type(8)));
typedef float    f32x4 __attribute__((ext_vector_type(4)));
typedef unsigned short u16x8 __attribute__((ext_vector_type(8)));

#define BB 8
#define SS 1024
#define EE 2048
#define HH 16
#define DD 128

__device__ __forceinline__ u16 f2bf(float f){
  union { float f; unsigned u; } v; v.f = f;
  unsigned r = v.u + 0x7FFFu + ((v.u >> 16) & 1u);
  return (u16)(r >> 16);
}
__device__ __forceinline__ float bf2f(u16 h){
  union { unsigned u; float f; } v; v.u = ((unsigned)h) << 16;
  return v.f;
}
__device__ __forceinline__ bf16x8 ld8(const u16* p){
  return __builtin_bit_cast(bf16x8, *(const u16x8*)p);
}

typedef __attribute__((address_space(1))) const unsigned int gas_u32;
typedef __attribute__((address_space(3))) unsigned int las_u32;
__device__ __forceinline__ void g2l16(const u16* g, u16* l){
  __builtin_amdgcn_global_load_lds((gas_u32*)g, (las_u32*)l, 16, 0, 0);
}

// ---------------- f32 -> bf16 convert (vectorized) ----------------
__global__ __launch_bounds__(256) void cvt_f32_bf16(const float* __restrict__ in,
                                                    u16* __restrict__ out, int n){
  int i = (blockIdx.x*256 + threadIdx.x)*8;
  if (i >= n) return;
  float4 v0 = *(const float4*)(in + i);
  float4 v1 = *(const float4*)(in + i + 4);
  u16x8 o;
  o[0]=f2bf(v0.x); o[1]=f2bf(v0.y); o[2]=f2bf(v0.z); o[3]=f2bf(v0.w);
  o[4]=f2bf(v1.x); o[5]=f2bf(v1.y); o[6]=f2bf(v1.z); o[7]=f2bf(v1.w);
  *(u16x8*)(out + i) = o;
}

// ---------------- W (KxN f32) -> Wt (NxK bf16), LDS-tiled ----------------
__global__ __launch_bounds__(256) void transposeW(const float* __restrict__ W,
                                                  u16* __restrict__ Wt, int K, int N){
  __shared__ float t[32][33];
  int c = threadIdx.x & 31, r = threadIdx.x >> 5; // r in 0..7
  int bx = blockIdx.x, by = blockIdx.y;           // bx along N, by along K
  #pragma unroll
  for (int i = 0; i < 32; i += 8)
    t[r+i][c] = W[(size_t)(by*32 + r + i)*N + bx*32 + c];
  __syncthreads();
  #pragma unroll
  for (int i = 0; i < 32; i += 8)
    Wt[(size_t)(bx*32 + r + i)*K + by*32 + c] = f2bf(t[c][r+i]);
}

// ---------------- RoPE tables: cos/sin[s][j], j=0..47 ----------------
__global__ __launch_bounds__(256) void rope_tables(float* __restrict__ cosb,
                                                   float* __restrict__ sinb){
  int i = blockIdx.x*256 + threadIdx.x;
  if (i >= SS*48) return;
  int s = i / 48, j = i % 48;
  float freq = powf(10000.0f, -((float)(2*j)) / 96.0f);
  float e = (float)s * freq;
  cosb[i] = cosf(e);
  sinb[i] = sinf(e);
}

// ---------------- RoPE apply in-place on [B*S][E] bf16 ----------------
__global__ __launch_bounds__(256) void rope_apply(u16* __restrict__ buf,
                                                  const float* __restrict__ cosb,
                                                  const float* __restrict__ sinb){
  int t = blockIdx.x*256 + threadIdx.x;   // B*S*H = 131072 threads
  int row = t >> 4, h = t & 15, s = row & (SS-1);
  u16* p = buf + (size_t)row*EE + h*DD + 32;  // 96-wide rope region
  float e[48], o[48];
  #pragma unroll
  for (int c = 0; c < 12; c++){
    u16x8 v = *(const u16x8*)(p + c*8);
    #pragma unroll
    for (int j = 0; j < 4; j++){
      e[c*4 + j] = bf2f(v[2*j]);
      o[c*4 + j] = bf2f(v[2*j+1]);
    }
  }
  u16 ob[96];
  #pragma unroll
  for (int j = 0; j < 48; j++){
    float cs = cosb[s*48 + j], sn = sinb[s*48 + j];
    ob[j]      = f2bf(e[j]*cs - o[j]*sn);
    ob[48 + j] = f2bf(o[j]*cs + e[j]*sn);
  }
  #pragma unroll
  for (int c = 0; c < 12; c++)
    *(u16x8*)(p + c*8) = *(const u16x8*)(ob + c*8);
}

// ---------------- GEMM (m97 structure): C = A[MxK] * Bt[NxK]^T, bf16, f32 acc ----------------
__global__ __launch_bounds__(256) void gemm_bt(const u16* __restrict__ A,
    const u16* __restrict__ Bt, u16* __restrict__ C, int M, int N, int K){
  __shared__ u16 Al[128*32];
  __shared__ u16 Bl[128*32];
  const int tid = threadIdx.x;
  const int lane = tid & 63, w = tid >> 6;
  const int wr = w >> 1, wc = w & 1;
  const int l15 = lane & 15, l4 = lane >> 4;
  const int bm = blockIdx.y*128, bn = blockIdx.x*128;
  const int srow = tid >> 2;        // 0..63
  const int skc  = (tid & 3) * 8;   // 0,8,16,24
  const u16* ga = A  + (size_t)(bm + srow)*K + skc;
  const u16* gb = Bt + (size_t)(bn + srow)*K + skc;
  u16* la = Al + w*512;             // wave-uniform LDS base (bytes: w*1024)
  u16* lb = Bl + w*512;
  f32x4 acc[4][4] = {};
  for (int k0 = 0; k0 < K; k0 += 32){
    __syncthreads();                // previous tile's readers done
    g2l16(ga + k0,          la);
    g2l16(ga + 64*K + k0,   la + 2048);
    g2l16(gb + k0,          lb);
    g2l16(gb + 64*K + k0,   lb + 2048);
    __syncthreads();                // vmcnt drained before barrier -> tile ready
    bf16x8 af[4], bfr[4];
    #pragma unroll
    for (int m = 0; m < 4; m++) af[m]  = ld8(Al + (wr*64 + m*16 + l15)*32 + l4*8);
    #pragma unroll
    for (int n = 0; n < 4; n++) bfr[n] = ld8(Bl + (wc*64 + n*16 + l15)*32 + l4*8);
    #pragma unroll
    for (int m = 0; m < 4; m++)
      #pragma unroll
      for (int n = 0; n < 4; n++)
        acc[m][n] = __builtin_amdgcn_mfma_f32_16x16x32_bf16(af[m], bfr[n], acc[m][n], 0, 0, 0);
  }
  #pragma unroll
  for (int m = 0; m < 4; m++)
    #pragma unroll
    for (int n = 0; n < 4; n++)
      #pragma unroll
      for (int r = 0; r < 4; r++){
        int row = bm + wr*64 + m*16 + l4*4 + r;
        int col = bn + wc*64 + n*16 + l15;
        C[(size_t)row*N + col] = f2bf(acc[m][n][r]);
      }
}

// ---------------- Flash attention v2: 8 waves x 16 q-rows (Q-tile 128), KV tile 64 ----------------
#define KLD 136  // K_lds row stride (elems): 272B -> 2-way-free b128 reads

__global__ __launch_bounds__(512) void attn(const u16* __restrict__ qp,
                                            const u16* __restrict__ kp,
                                            const u16* __restrict__ vp,
                                            float* __restrict__ out){
  __shared__ u16 Kl[64*KLD];      // 17408 B
  __shared__ u16 Vt[128*64];      // 16384 B, transposed + XOR chunk swizzle
  __shared__ u16 Pl[8][16*72];    // 18432 B, wave-private P staging
  const int tid = threadIdx.x, lane = tid & 63, w = tid >> 6;
  const int l15 = lane & 15, l4 = lane >> 4;
  const int qt = 7 - blockIdx.y;                 // heavy blocks dispatch first
  const int bh = blockIdx.x;
  const int b = bh >> 4, h = bh & 15;
  const int qbase = qt*128;
  const int qmin = qbase + w*16;
  const int srow = tid >> 3, sseg = tid & 7, d0 = sseg*16;
  const float c = 0.12751920700948998f;          // (1/sqrt(128)) * log2(e)

  // Q fragments (16 rows per wave)
  const size_t rowq = (size_t)(b*SS + qmin + l15)*EE + h*DD;
  bf16x8 qf[4];
  #pragma unroll
  for (int kk = 0; kk < 4; kk++) qf[kk] = ld8(qp + rowq + kk*32 + l4*8);

  f32x4 ao[8] = {};
  float mi[4], li[4];
  #pragma unroll
  for (int r = 0; r < 4; r++){ mi[r] = -3e38f; li[r] = 0.0f; }

  const int ntiles = 2*qt + 2;
  const int cb = ((srow >> 3) ^ ((sseg*2) & 7)) & 7;  // hoisted swizzle base
  // prologue: load tile 0 into regs
  u16x8 kr0, kr1, vr0, vr1;
  {
    const u16* kg = kp + (size_t)(b*SS + srow)*EE + h*DD + d0;
    const u16* vg = vp + (size_t)(b*SS + srow)*EE + h*DD + d0;
    kr0 = *(const u16x8*)kg;     kr1 = *(const u16x8*)(kg + 8);
    vr0 = *(const u16x8*)vg;     vr1 = *(const u16x8*)(vg + 8);
  }

  for (int t = 0; t < ntiles; t++){
    const int kv0 = t*64;
    __syncthreads();              // previous tile's LDS readers done
    *(u16x8*)(Kl + srow*KLD + d0)     = kr0;
    *(u16x8*)(Kl + srow*KLD + d0 + 8) = kr1;
    {
      u16* vbase = Vt + (size_t)d0*64 + (srow & 7);
      #pragma unroll
      for (int j = 0; j < 16; j++){
        int chunk = (cb ^ (j & 7) ^ (j >> 3)) & 7;
        u16 val = (j < 8) ? vr0[j] : vr1[j - 8];
        vbase[j*64 + chunk*8] = val;
      }
    }
    __syncthreads();              // tile staged
    if (t + 1 < ntiles){          // pipelined prefetch of next tile
      const u16* kg = kp + (size_t)(b*SS + kv0 + 64 + srow)*EE + h*DD + d0;
      const u16* vg = vp + (size_t)(b*SS + kv0 + 64 + srow)*EE + h*DD + d0;
      kr0 = *(const u16x8*)kg;   kr1 = *(const u16x8*)(kg + 8);
      vr0 = *(const u16x8*)vg;   vr1 = *(const u16x8*)(vg + 8);
    }
    if (kv0 <= qmin + 15){        // wave participates in this tile
      // QK^T
      float sv[4][4];
      #pragma unroll
      for (int nt = 0; nt < 4; nt++){
        f32x4 sacc = {};
        #pragma unroll
        for (int kk = 0; kk < 4; kk++){
          bf16x8 kf = ld8(Kl + (nt*16 + l15)*KLD + kk*32 + l4*8);
          sacc = __builtin_amdgcn_mfma_f32_16x16x32_bf16(qf[kk], kf, sacc, 0, 0, 0);
        }
        #pragma unroll
        for (int r = 0; r < 4; r++) sv[nt][r] = sacc[r];
      }
      if (kv0 + 63 > qmin){       // diagonal tile: apply causal mask
        #pragma unroll
        for (int nt = 0; nt < 4; nt++)
          #pragma unroll
          for (int r = 0; r < 4; r++){
            int qg = qmin + l4*4 + r;
            int kg_ = kv0 + nt*16 + l15;
            if (kg_ > qg) sv[nt][r] = -3e38f;
          }
      }
      // online softmax in exp2 domain
      float pout[4][4];
      #pragma unroll
      for (int r = 0; r < 4; r++){
        float mx = fmaxf(fmaxf(sv[0][r], sv[1][r]), fmaxf(sv[2][r], sv[3][r]));
        #pragma unroll
        for (int off = 1; off < 16; off <<= 1) mx = fmaxf(mx, __shfl_xor(mx, off));
        float mnew = fmaxf(mi[r], mx);
        float mnc = mnew * c;
        float alpha = __builtin_amdgcn_exp2f(__builtin_fmaf(mi[r], c, -mnc));
        float rs = 0.0f;
        #pragma unroll
        for (int nt = 0; nt < 4; nt++){
          float pv = __builtin_amdgcn_exp2f(__builtin_fmaf(sv[nt][r], c, -mnc));
          pout[nt][r] = pv; rs += pv;
        }
        #pragma unroll
        for (int off = 1; off < 16; off <<= 1) rs += __shfl_xor(rs, off);
        li[r] = li[r]*alpha + rs;
        mi[r] = mnew;
        #pragma unroll
        for (int n8 = 0; n8 < 8; n8++) ao[n8][r] *= alpha;
      }
      // P -> wave-private LDS (bf16), then PV
      #pragma unroll
      for (int nt = 0; nt < 4; nt++)
        #pragma unroll
        for (int r = 0; r < 4; r++)
          Pl[w][(l4*4 + r)*72 + nt*16 + l15] = f2bf(pout[nt][r]);
      #pragma unroll
      for (int kk = 0; kk < 2; kk++){
        bf16x8 pa = ld8(&Pl[w][l15*72 + kk*32 + l4*8]);
        #pragma unroll
        for (int n8 = 0; n8 < 8; n8++){
          int d = n8*16 + l15;
          int kvc = kk*4 + l4;
          int chunk = (kvc ^ (d & 7) ^ ((d >> 3) & 7)) & 7;
          bf16x8 vf = ld8(Vt + d*64 + chunk*8);
          ao[n8] = __builtin_amdgcn_mfma_f32_16x16x32_bf16(pa, vf, ao[n8], 0, 0, 0);
        }
      }
    }
  }

  // epilogue: out[b][s][h*128+d] f32
  #pragma unroll
  for (int r = 0; r < 4; r++){
    float inv = 1.0f / li[r];
    size_t orow = (size_t)(b*SS + qmin + l4*4 + r)*EE + h*DD;
    #pragma unroll
    for (int n8 = 0; n8 < 8; n8++)
      out[orow + n8*16 + l15] = ao[n8][r]*inv;
  }
}

// ---------------- launch ----------------
extern "C" void kernel_launch(void* const* d_in, const int* in_sizes, int n_in,
                              void* d_out, int out_size, void* d_ws, size_t ws_size,
                              hipStream_t stream){
  const float* x    = (const float*)d_in[0];
  const float* Wq   = (const float*)d_in[1];
  const float* Wkvd = (const float*)d_in[2];
  const float* Wku  = (const float*)d_in[3];
  const float* Wvu  = (const float*)d_in[4];
  float* out = (float*)d_out;
  char* ws = (char*)d_ws;

  u16*   xb    = (u16*)  (ws);                 // 33,554,432 B
  u16*   WqT   = (u16*)  (ws +  33554432);     //  8,388,608
  u16*   WkvdT = (u16*)  (ws +  41943040);     //  2,097,152
  u16*   WkuT  = (u16*)  (ws +  44040192);     //  2,097,152
  u16*   WvuT  = (u16*)  (ws +  46137344);     //  2,097,152
  float* cosb  = (float*)(ws +  48234496);     //    196,608
  float* sinb  = (float*)(ws +  48431104);     //    196,608
  u16*   qp    = (u16*)  (ws +  48627712);     // 33,554,432
  u16*   ckv   = (u16*)  (ws +  82182144);     //  8,388,608
  u16*   kp    = (u16*)  (ws +  90570752);     // 33,554,432
  u16*   vp    = (u16*)  (ws + 124125184);     // 33,554,432  (end 157,679,616)

  cvt_f32_bf16<<<(BB*SS*EE)/(256*8), 256, 0, stream>>>(x, xb, BB*SS*EE);
  transposeW<<<dim3(EE/32,  EE/32), 256, 0, stream>>>(Wq,   WqT,   EE,  EE);
  transposeW<<<dim3(512/32, EE/32), 256, 0, stream>>>(Wkvd, WkvdT, EE,  512);
  transposeW<<<dim3(EE/32, 512/32), 256, 0, stream>>>(Wku,  WkuT,  512, EE);
  transposeW<<<dim3(EE/32, 512/32), 256, 0, stream>>>(Wvu,  WvuT,  512, EE);
  rope_tables<<<(SS*48 + 255)/256, 256, 0, stream>>>(cosb, sinb);

  gemm_bt<<<dim3(EE/128,  (BB*SS)/128), 256, 0, stream>>>(xb,  WqT,   qp,  BB*SS, EE,  EE);
  gemm_bt<<<dim3(512/128, (BB*SS)/128), 256, 0, stream>>>(xb,  WkvdT, ckv, BB*SS, 512, EE);
  gemm_bt<<<dim3(EE/128,  (BB*SS)/128), 256, 0, stream>>>(ckv, WkuT,  kp,  BB*SS, EE,  512);
  gemm_bt<<<dim3(EE/128,  (BB*SS)/128), 256, 0, stream>>>(ckv, WvuT,  vp,  BB*SS, EE,  512);

  rope_apply<<<(BB*SS*HH)/256, 256, 0, stream>>>(qp, cosb, sinb);
  rope_apply<<<(BB*SS*HH)/256, 256, 0, stream>>>(kp, cosb, sinb);

  attn<<<dim3(BB*HH, SS/128), 512, 0, stream>>>(qp, kp, vp, out);
}

// Round 3
// 334.910 us; speedup vs baseline: 1.5649x; 1.1711x over previous
//
#include <hip/hip_runtime.h>
#include <stdint.h>

typedef unsigned short u16;
typedef __bf16 bf16x8 __attribute__((ext_vector_type(8)));
typedef float    f32x4 __attribute__((ext_vector_type(4)));
typedef unsigned short u16x8 __attribute__((ext_vector_type(8)));

#define BB 8
#define SS 1024
#define EE 2048
#define HH 16
#define DD 128

__device__ __forceinline__ u16 f2bf(float f){
  union { float f; unsigned u; } v; v.f = f;
  unsigned r = v.u + 0x7FFFu + ((v.u >> 16) & 1u);
  return (u16)(r >> 16);
}
__device__ __forceinline__ float bf2f(u16 h){
  union { unsigned u; float f; } v; v.u = ((unsigned)h) << 16;
  return v.f;
}
__device__ __forceinline__ bf16x8 ld8(const u16* p){
  return __builtin_bit_cast(bf16x8, *(const u16x8*)p);
}

typedef __attribute__((address_space(1))) const unsigned int gas_u32;
typedef __attribute__((address_space(3))) unsigned int las_u32;
__device__ __forceinline__ void g2l16(const u16* g, u16* l){
  __builtin_amdgcn_global_load_lds((gas_u32*)g, (las_u32*)l, 16, 0, 0);
}

// ---------------- f32 -> bf16 convert (vectorized) ----------------
__global__ __launch_bounds__(256) void cvt_f32_bf16(const float* __restrict__ in,
                                                    u16* __restrict__ out, int n){
  int i = (blockIdx.x*256 + threadIdx.x)*8;
  if (i >= n) return;
  float4 v0 = *(const float4*)(in + i);
  float4 v1 = *(const float4*)(in + i + 4);
  u16x8 o;
  o[0]=f2bf(v0.x); o[1]=f2bf(v0.y); o[2]=f2bf(v0.z); o[3]=f2bf(v0.w);
  o[4]=f2bf(v1.x); o[5]=f2bf(v1.y); o[6]=f2bf(v1.z); o[7]=f2bf(v1.w);
  *(u16x8*)(out + i) = o;
}

// ---------------- W (KxN f32) -> Wt (NxK bf16), LDS-tiled ----------------
__global__ __launch_bounds__(256) void transposeW(const float* __restrict__ W,
                                                  u16* __restrict__ Wt, int K, int N){
  __shared__ float t[32][33];
  int c = threadIdx.x & 31, r = threadIdx.x >> 5; // r in 0..7
  int bx = blockIdx.x, by = blockIdx.y;           // bx along N, by along K
  #pragma unroll
  for (int i = 0; i < 32; i += 8)
    t[r+i][c] = W[(size_t)(by*32 + r + i)*N + bx*32 + c];
  __syncthreads();
  #pragma unroll
  for (int i = 0; i < 32; i += 8)
    Wt[(size_t)(bx*32 + r + i)*K + by*32 + c] = f2bf(t[c][r+i]);
}

// ---------------- RoPE tables: cos/sin[s][j], j=0..47 ----------------
__global__ __launch_bounds__(256) void rope_tables(float* __restrict__ cosb,
                                                   float* __restrict__ sinb){
  int i = blockIdx.x*256 + threadIdx.x;
  if (i >= SS*48) return;
  int s = i / 48, j = i % 48;
  float freq = powf(10000.0f, -((float)(2*j)) / 96.0f);
  float e = (float)s * freq;
  cosb[i] = cosf(e);
  sinb[i] = sinf(e);
}

// ---------------- RoPE apply in-place on [B*S][E] bf16 ----------------
__global__ __launch_bounds__(256) void rope_apply(u16* __restrict__ buf,
                                                  const float* __restrict__ cosb,
                                                  const float* __restrict__ sinb){
  int t = blockIdx.x*256 + threadIdx.x;   // B*S*H = 131072 threads
  int row = t >> 4, h = t & 15, s = row & (SS-1);
  u16* p = buf + (size_t)row*EE + h*DD + 32;  // 96-wide rope region
  float e[48], o[48];
  #pragma unroll
  for (int c = 0; c < 12; c++){
    u16x8 v = *(const u16x8*)(p + c*8);
    #pragma unroll
    for (int j = 0; j < 4; j++){
      e[c*4 + j] = bf2f(v[2*j]);
      o[c*4 + j] = bf2f(v[2*j+1]);
    }
  }
  u16 ob[96];
  #pragma unroll
  for (int j = 0; j < 48; j++){
    float cs = cosb[s*48 + j], sn = sinb[s*48 + j];
    ob[j]      = f2bf(e[j]*cs - o[j]*sn);
    ob[48 + j] = f2bf(o[j]*cs + e[j]*sn);
  }
  #pragma unroll
  for (int c = 0; c < 12; c++)
    *(u16x8*)(p + c*8) = *(const u16x8*)(ob + c*8);
}

// ---------------- GEMM 128^2 (m97 structure) for N=512 case ----------------
__global__ __launch_bounds__(256) void gemm_bt(const u16* __restrict__ A,
    const u16* __restrict__ Bt, u16* __restrict__ C, int M, int N, int K){
  __shared__ u16 Al[128*32];
  __shared__ u16 Bl[128*32];
  const int tid = threadIdx.x;
  const int lane = tid & 63, w = tid >> 6;
  const int wr = w >> 1, wc = w & 1;
  const int l15 = lane & 15, l4 = lane >> 4;
  const int bm = blockIdx.y*128, bn = blockIdx.x*128;
  const int srow = tid >> 2;        // 0..63
  const int skc  = (tid & 3) * 8;   // 0,8,16,24
  const u16* ga = A  + (size_t)(bm + srow)*K + skc;
  const u16* gb = Bt + (size_t)(bn + srow)*K + skc;
  u16* la = Al + w*512;             // wave-uniform LDS base
  u16* lb = Bl + w*512;
  f32x4 acc[4][4] = {};
  for (int k0 = 0; k0 < K; k0 += 32){
    __syncthreads();
    g2l16(ga + k0,          la);
    g2l16(ga + 64*K + k0,   la + 2048);
    g2l16(gb + k0,          lb);
    g2l16(gb + 64*K + k0,   lb + 2048);
    __syncthreads();
    bf16x8 af[4], bfr[4];
    #pragma unroll
    for (int m = 0; m < 4; m++) af[m]  = ld8(Al + (wr*64 + m*16 + l15)*32 + l4*8);
    #pragma unroll
    for (int n = 0; n < 4; n++) bfr[n] = ld8(Bl + (wc*64 + n*16 + l15)*32 + l4*8);
    #pragma unroll
    for (int m = 0; m < 4; m++)
      #pragma unroll
      for (int n = 0; n < 4; n++)
        acc[m][n] = __builtin_amdgcn_mfma_f32_16x16x32_bf16(af[m], bfr[n], acc[m][n], 0, 0, 0);
  }
  #pragma unroll
  for (int m = 0; m < 4; m++)
    #pragma unroll
    for (int n = 0; n < 4; n++)
      #pragma unroll
      for (int r = 0; r < 4; r++){
        int row = bm + wr*64 + m*16 + l4*4 + r;
        int col = bn + wc*64 + n*16 + l15;
        C[(size_t)row*N + col] = f2bf(acc[m][n][r]);
      }
}

// ---------------- GEMM 256^2, 8-phase double-buffered, counted vmcnt ----------------
// C = A[MxK] * Bt[NxK]^T. Output split: cols < nsplit -> C0, else C1 (row stride Nout).
#define BARRIER() asm volatile("s_barrier" ::: "memory")
#define VMCNT4()  asm volatile("s_waitcnt vmcnt(4)" ::: "memory")

// conflict-free XOR swizzle: within a [128][64]-elem half-tile, 16B-chunk c of
// row r is stored at chunk (c ^ (r&7)). Staged via pre-swizzled global source
// (rule #21: linear gload_lds dest + inverse-swizzled source + swizzled read).
#define AFR(buf, mf, ks) ld8(&AL[buf][wr][((mf)*16 + l15)*64 + ((((ks)*4 + l4) ^ r7) << 3)])
#define BFR(buf, nf, ks) ld8(&BL[buf][wc>>1][(((wc&1)*64 + (nf)*16 + l15))*64 + ((((ks)*4 + l4) ^ r7) << 3)])

#define STAGE_A(buf, h, kt) stage2(aRow, (h), (kt), K, &AL[buf][h][0], wj0)
#define STAGE_B(buf, h, kt) stage2(bRow, (h), (kt), K, &BL[buf][h][0], wj0)

__device__ __forceinline__ void stage2(const u16* rowbase, int h, int kt, int K,
                                       u16* lds, int wj0){
  const u16* g = rowbase + (size_t)h*128*K + kt*64;
  g2l16(g,               lds + wj0*512);
  g2l16(g + (size_t)8*K, lds + wj0*512 + 512);
}

#define PHASE(buf, q, LOADB, STAGE, VM) do{                                        \
  bf16x8 a00 = AFR(buf, 2*(q)  , 0);                                              \
  bf16x8 a01 = AFR(buf, 2*(q)  , 1);                                              \
  bf16x8 a10 = AFR(buf, 2*(q)+1, 0);                                              \
  bf16x8 a11 = AFR(buf, 2*(q)+1, 1);                                              \
  if (LOADB){                                                                      \
    _Pragma("unroll")                                                              \
    for (int nf = 0; nf < 4; nf++){ bq[nf][0]=BFR(buf,nf,0); bq[nf][1]=BFR(buf,nf,1); } \
  }                                                                                \
  STAGE;                                                                           \
  if (VM) VMCNT4();                                                                \
  BARRIER();                                                                       \
  __builtin_amdgcn_s_setprio(1);                                                   \
  _Pragma("unroll")                                                                \
  for (int nf = 0; nf < 4; nf++){                                                  \
    acc[2*(q)][nf]   = __builtin_amdgcn_mfma_f32_16x16x32_bf16(a00, bq[nf][0], acc[2*(q)][nf],0,0,0);   \
    acc[2*(q)+1][nf] = __builtin_amdgcn_mfma_f32_16x16x32_bf16(a10, bq[nf][0], acc[2*(q)+1][nf],0,0,0); \
  }                                                                                \
  _Pragma("unroll")                                                                \
  for (int nf = 0; nf < 4; nf++){                                                  \
    acc[2*(q)][nf]   = __builtin_amdgcn_mfma_f32_16x16x32_bf16(a01, bq[nf][1], acc[2*(q)][nf],0,0,0);   \
    acc[2*(q)+1][nf] = __builtin_amdgcn_mfma_f32_16x16x32_bf16(a11, bq[nf][1], acc[2*(q)+1][nf],0,0,0); \
  }                                                                                \
  __builtin_amdgcn_s_setprio(0);                                                   \
  BARRIER();                                                                       \
  __builtin_amdgcn_sched_barrier(0);                                               \
}while(0)

__global__ __launch_bounds__(512, 2) void gemm8(const u16* __restrict__ A,
    const u16* __restrict__ Bt, u16* __restrict__ C0, u16* __restrict__ C1,
    int K, int Nout, int nsplit){
  __shared__ u16 AL[2][2][128*64];   // [buf][half][row*64 + chunk*8] (swizzled)
  __shared__ u16 BL[2][2][128*64];
  const int tid = threadIdx.x, lane = tid & 63, w = tid >> 6;
  const int wr = w >> 2, wc = w & 3;            // 2M x 4N wave grid
  const int l15 = lane & 15, l4 = lane >> 4;
  const int r7 = l15 & 7;
  const int bm = blockIdx.y*256, bn = blockIdx.x*256;
  const int wj0 = w*2;
  const int cswz = (lane & 7) ^ (lane >> 3);    // pre-swizzled source chunk
  const u16* aRow = A  + (size_t)(bm + wj0*8 + (lane>>3))*K + cswz*8;
  const u16* bRow = Bt + (size_t)(bn + wj0*8 + (lane>>3))*K + cswz*8;

  const int nkt = K >> 6;            // 64-wide K-tiles
  const int niter = nkt >> 1;

  // prologue: A0,B0 (buf0) + B1 (buf1); A1 staged in iter0 ph1-2
  STAGE_A(0, 0, 0); STAGE_A(0, 1, 0);
  STAGE_B(0, 0, 0); STAGE_B(0, 1, 0);
  STAGE_B(1, 0, 1); STAGE_B(1, 1, 1);
  VMCNT4();                          // A0,B0 complete; B1 (4 loads) in flight
  BARRIER();

  f32x4 acc[8][4] = {};
  bf16x8 bq[4][2];

  for (int it = 0; it < niter; ++it){
    const int kto = 2*it + 1;
    int kt2 = 2*it + 2; if (kt2 >= nkt) kt2 -= nkt;   // wrap: harmless re-read
    int kt3 = 2*it + 3; if (kt3 >= nkt) kt3 -= nkt;
    PHASE(0, 0, 1, STAGE_A(1, 0, kto), 0);
    PHASE(0, 1, 0, STAGE_A(1, 1, kto), 0);
    PHASE(0, 2, 0, STAGE_B(0, 0, kt2), 0);
    PHASE(0, 3, 0, STAGE_B(0, 1, kt2), 1);
    PHASE(1, 0, 1, STAGE_A(0, 0, kt2), 0);
    PHASE(1, 1, 0, STAGE_A(0, 1, kt2), 0);
    PHASE(1, 2, 0, STAGE_B(1, 0, kt3), 0);
    PHASE(1, 3, 0, STAGE_B(1, 1, kt3), 1);
  }
  asm volatile("s_waitcnt vmcnt(0)" ::: "memory");  // drain before block exit

  u16* Cd = (bn < nsplit) ? C0 : C1;
  const int bcol = (bn < nsplit) ? bn : bn - nsplit;
  #pragma unroll
  for (int mf = 0; mf < 8; mf++)
    #pragma unroll
    for (int nf = 0; nf < 4; nf++)
      #pragma unroll
      for (int r = 0; r < 4; r++){
        int row = bm + wr*128 + mf*16 + l4*4 + r;
        int col = bcol + wc*64 + nf*16 + l15;
        Cd[(size_t)row*Nout + col] = f2bf(acc[mf][nf][r]);
      }
}

// ---------------- Flash attention: 8 waves x 16 q-rows (Q-tile 128), KV tile 64 ----------------
#define KLD 136

__global__ __launch_bounds__(512) void attn(const u16* __restrict__ qp,
                                            const u16* __restrict__ kp,
                                            const u16* __restrict__ vp,
                                            float* __restrict__ out){
  __shared__ u16 Kl[64*KLD];
  __shared__ u16 Vt[128*64];
  __shared__ u16 Pl[8][16*72];
  const int tid = threadIdx.x, lane = tid & 63, w = tid >> 6;
  const int l15 = lane & 15, l4 = lane >> 4;
  const int qt = 7 - blockIdx.y;
  const int bh = blockIdx.x;
  const int b = bh >> 4, h = bh & 15;
  const int qbase = qt*128;
  const int qmin = qbase + w*16;
  const int srow = tid >> 3, sseg = tid & 7, d0 = sseg*16;
  const float c = 0.12751920700948998f;          // (1/sqrt(128)) * log2(e)

  const size_t rowq = (size_t)(b*SS + qmin + l15)*EE + h*DD;
  bf16x8 qf[4];
  #pragma unroll
  for (int kk = 0; kk < 4; kk++) qf[kk] = ld8(qp + rowq + kk*32 + l4*8);

  f32x4 ao[8] = {};
  float mi[4], li[4];
  #pragma unroll
  for (int r = 0; r < 4; r++){ mi[r] = -3e38f; li[r] = 0.0f; }

  const int ntiles = 2*qt + 2;
  const int cb = ((srow >> 3) ^ ((sseg*2) & 7)) & 7;
  u16x8 kr0, kr1, vr0, vr1;
  {
    const u16* kg = kp + (size_t)(b*SS + srow)*EE + h*DD + d0;
    const u16* vg = vp + (size_t)(b*SS + srow)*EE + h*DD + d0;
    kr0 = *(const u16x8*)kg;     kr1 = *(const u16x8*)(kg + 8);
    vr0 = *(const u16x8*)vg;     vr1 = *(const u16x8*)(vg + 8);
  }

  for (int t = 0; t < ntiles; t++){
    const int kv0 = t*64;
    __syncthreads();
    *(u16x8*)(Kl + srow*KLD + d0)     = kr0;
    *(u16x8*)(Kl + srow*KLD + d0 + 8) = kr1;
    {
      u16* vbase = Vt + (size_t)d0*64 + (srow & 7);
      #pragma unroll
      for (int j = 0; j < 16; j++){
        int chunk = (cb ^ (j & 7) ^ (j >> 3)) & 7;
        u16 val = (j < 8) ? vr0[j] : vr1[j - 8];
        vbase[j*64 + chunk*8] = val;
      }
    }
    __syncthreads();
    if (t + 1 < ntiles){
      const u16* kg = kp + (size_t)(b*SS + kv0 + 64 + srow)*EE + h*DD + d0;
      const u16* vg = vp + (size_t)(b*SS + kv0 + 64 + srow)*EE + h*DD + d0;
      kr0 = *(const u16x8*)kg;   kr1 = *(const u16x8*)(kg + 8);
      vr0 = *(const u16x8*)vg;   vr1 = *(const u16x8*)(vg + 8);
    }
    if (kv0 <= qmin + 15){
      float sv[4][4];
      #pragma unroll
      for (int nt = 0; nt < 4; nt++){
        f32x4 sacc = {};
        #pragma unroll
        for (int kk = 0; kk < 4; kk++){
          bf16x8 kf = ld8(Kl + (nt*16 + l15)*KLD + kk*32 + l4*8);
          sacc = __builtin_amdgcn_mfma_f32_16x16x32_bf16(qf[kk], kf, sacc, 0, 0, 0);
        }
        #pragma unroll
        for (int r = 0; r < 4; r++) sv[nt][r] = sacc[r];
      }
      if (kv0 + 63 > qmin){
        #pragma unroll
        for (int nt = 0; nt < 4; nt++)
          #pragma unroll
          for (int r = 0; r < 4; r++){
            int qg = qmin + l4*4 + r;
            int kg_ = kv0 + nt*16 + l15;
            if (kg_ > qg) sv[nt][r] = -3e38f;
          }
      }
      float pout[4][4];
      #pragma unroll
      for (int r = 0; r < 4; r++){
        float mx = fmaxf(fmaxf(sv[0][r], sv[1][r]), fmaxf(sv[2][r], sv[3][r]));
        #pragma unroll
        for (int off = 1; off < 16; off <<= 1) mx = fmaxf(mx, __shfl_xor(mx, off));
        float mnew = fmaxf(mi[r], mx);
        float mnc = mnew * c;
        float alpha = __builtin_amdgcn_exp2f(__builtin_fmaf(mi[r], c, -mnc));
        float rs = 0.0f;
        #pragma unroll
        for (int nt = 0; nt < 4; nt++){
          float pv = __builtin_amdgcn_exp2f(__builtin_fmaf(sv[nt][r], c, -mnc));
          pout[nt][r] = pv; rs += pv;
        }
        #pragma unroll
        for (int off = 1; off < 16; off <<= 1) rs += __shfl_xor(rs, off);
        li[r] = li[r]*alpha + rs;
        mi[r] = mnew;
        #pragma unroll
        for (int n8 = 0; n8 < 8; n8++) ao[n8][r] *= alpha;
      }
      #pragma unroll
      for (int nt = 0; nt < 4; nt++)
        #pragma unroll
        for (int r = 0; r < 4; r++)
          Pl[w][(l4*4 + r)*72 + nt*16 + l15] = f2bf(pout[nt][r]);
      #pragma unroll
      for (int kk = 0; kk < 2; kk++){
        bf16x8 pa = ld8(&Pl[w][l15*72 + kk*32 + l4*8]);
        #pragma unroll
        for (int n8 = 0; n8 < 8; n8++){
          int d = n8*16 + l15;
          int kvc = kk*4 + l4;
          int chunk = (kvc ^ (d & 7) ^ ((d >> 3) & 7)) & 7;
          bf16x8 vf = ld8(Vt + d*64 + chunk*8);
          ao[n8] = __builtin_amdgcn_mfma_f32_16x16x32_bf16(pa, vf, ao[n8], 0, 0, 0);
        }
      }
    }
  }

  #pragma unroll
  for (int r = 0; r < 4; r++){
    float inv = 1.0f / li[r];
    size_t orow = (size_t)(b*SS + qmin + l4*4 + r)*EE + h*DD;
    #pragma unroll
    for (int n8 = 0; n8 < 8; n8++)
      out[orow + n8*16 + l15] = ao[n8][r]*inv;
  }
}

// ---------------- launch ----------------
extern "C" void kernel_launch(void* const* d_in, const int* in_sizes, int n_in,
                              void* d_out, int out_size, void* d_ws, size_t ws_size,
                              hipStream_t stream){
  const float* x    = (const float*)d_in[0];
  const float* Wq   = (const float*)d_in[1];
  const float* Wkvd = (const float*)d_in[2];
  const float* Wku  = (const float*)d_in[3];
  const float* Wvu  = (const float*)d_in[4];
  float* out = (float*)d_out;
  char* ws = (char*)d_ws;

  u16*   xb    = (u16*)  (ws);                 // 33,554,432 B
  u16*   WqT   = (u16*)  (ws +  33554432);     //  8,388,608
  u16*   WkvdT = (u16*)  (ws +  41943040);     //  2,097,152
  u16*   WkuT  = (u16*)  (ws +  44040192);     //  2,097,152 (WvuT adjacent -> 4096xK panel)
  u16*   WvuT  = (u16*)  (ws +  46137344);     //  2,097,152
  float* cosb  = (float*)(ws +  48234496);     //    196,608
  float* sinb  = (float*)(ws +  48431104);     //    196,608
  u16*   qp    = (u16*)  (ws +  48627712);     // 33,554,432
  u16*   ckv   = (u16*)  (ws +  82182144);     //  8,388,608
  u16*   kp    = (u16*)  (ws +  90570752);     // 33,554,432
  u16*   vp    = (u16*)  (ws + 124125184);     // 33,554,432

  cvt_f32_bf16<<<(BB*SS*EE)/(256*8), 256, 0, stream>>>(x, xb, BB*SS*EE);
  transposeW<<<dim3(EE/32,  EE/32), 256, 0, stream>>>(Wq,   WqT,   EE,  EE);
  transposeW<<<dim3(512/32, EE/32), 256, 0, stream>>>(Wkvd, WkvdT, EE,  512);
  transposeW<<<dim3(EE/32, 512/32), 256, 0, stream>>>(Wku,  WkuT,  512, EE);
  transposeW<<<dim3(EE/32, 512/32), 256, 0, stream>>>(Wvu,  WvuT,  512, EE);
  rope_tables<<<(SS*48 + 255)/256, 256, 0, stream>>>(cosb, sinb);

  // q = x @ Wq  (M=8192, N=2048, K=2048) — 256^2 8-phase
  gemm8<<<dim3(EE/256, (BB*SS)/256), 512, 0, stream>>>(xb, WqT, qp, qp, EE, EE, EE);
  // c_kv = x @ Wkv_down (N=512) — 128^2
  gemm_bt<<<dim3(512/128, (BB*SS)/128), 256, 0, stream>>>(xb, WkvdT, ckv, BB*SS, 512, EE);
  // fused k/v up-projection: Bt = [WkuT; WvuT] (N=4096, K=512), split outputs
  gemm8<<<dim3(4096/256, (BB*SS)/256), 512, 0, stream>>>(ckv, WkuT, kp, vp, 512, EE, EE);

  rope_apply<<<(BB*SS*HH)/256, 256, 0, stream>>>(qp, cosb, sinb);
  rope_apply<<<(BB*SS*HH)/256, 256, 0, stream>>>(kp, cosb, sinb);

  attn<<<dim3(BB*HH, SS/128), 512, 0, stream>>>(qp, kp, vp, out);
}

// Round 4
// 325.713 us; speedup vs baseline: 1.6090x; 1.0282x over previous
//
#include <hip/hip_runtime.h>
#include <stdint.h>

typedef unsigned short u16;
typedef __bf16 bf16x8 __attribute__((ext_vector_type(8)));
typedef float    f32x4 __attribute__((ext_vector_type(4)));
typedef unsigned short u16x8 __attribute__((ext_vector_type(8)));
typedef unsigned short u16x4 __attribute__((ext_vector_type(4)));

#define BB 8
#define SS 1024
#define EE 2048
#define HH 16
#define DD 128

__device__ __forceinline__ u16 f2bf(float f){
  union { float f; unsigned u; } v; v.f = f;
  unsigned r = v.u + 0x7FFFu + ((v.u >> 16) & 1u);
  return (u16)(r >> 16);
}
__device__ __forceinline__ float bf2f(u16 h){
  union { unsigned u; float f; } v; v.u = ((unsigned)h) << 16;
  return v.f;
}
__device__ __forceinline__ bf16x8 ld8(const u16* p){
  return __builtin_bit_cast(bf16x8, *(const u16x8*)p);
}

typedef __attribute__((address_space(1))) const unsigned int gas_u32;
typedef __attribute__((address_space(3))) unsigned int las_u32;
__device__ __forceinline__ void g2l16(const u16* g, u16* l){
  __builtin_amdgcn_global_load_lds((gas_u32*)g, (las_u32*)l, 16, 0, 0);
}

#define BARRIER() asm volatile("s_barrier" ::: "memory")
#define VMC(n)    asm volatile("s_waitcnt vmcnt(" #n ")" ::: "memory")

// ---------------- f32 -> bf16 convert (vectorized) ----------------
__global__ __launch_bounds__(256) void cvt_f32_bf16(const float* __restrict__ in,
                                                    u16* __restrict__ out, int n){
  int i = (blockIdx.x*256 + threadIdx.x)*8;
  if (i >= n) return;
  float4 v0 = *(const float4*)(in + i);
  float4 v1 = *(const float4*)(in + i + 4);
  u16x8 o;
  o[0]=f2bf(v0.x); o[1]=f2bf(v0.y); o[2]=f2bf(v0.z); o[3]=f2bf(v0.w);
  o[4]=f2bf(v1.x); o[5]=f2bf(v1.y); o[6]=f2bf(v1.z); o[7]=f2bf(v1.w);
  *(u16x8*)(out + i) = o;
}

// ---------------- W (KxN f32) -> Wt (NxK bf16), LDS-tiled ----------------
__global__ __launch_bounds__(256) void transposeW(const float* __restrict__ W,
                                                  u16* __restrict__ Wt, int K, int N){
  __shared__ float t[32][33];
  int c = threadIdx.x & 31, r = threadIdx.x >> 5;
  int bx = blockIdx.x, by = blockIdx.y;
  #pragma unroll
  for (int i = 0; i < 32; i += 8)
    t[r+i][c] = W[(size_t)(by*32 + r + i)*N + bx*32 + c];
  __syncthreads();
  #pragma unroll
  for (int i = 0; i < 32; i += 8)
    Wt[(size_t)(bx*32 + r + i)*K + by*32 + c] = f2bf(t[c][r+i]);
}

// ---------------- RoPE tables ----------------
__global__ __launch_bounds__(256) void rope_tables(float* __restrict__ cosb,
                                                   float* __restrict__ sinb){
  int i = blockIdx.x*256 + threadIdx.x;
  if (i >= SS*48) return;
  int s = i / 48, j = i % 48;
  float freq = powf(10000.0f, -((float)(2*j)) / 96.0f);
  float e = (float)s * freq;
  cosb[i] = cosf(e);
  sinb[i] = sinf(e);
}

// ---------------- RoPE apply in-place on [B*S][E] bf16 ----------------
__global__ __launch_bounds__(256) void rope_apply(u16* __restrict__ buf,
                                                  const float* __restrict__ cosb,
                                                  const float* __restrict__ sinb){
  int t = blockIdx.x*256 + threadIdx.x;
  int row = t >> 4, h = t & 15, s = row & (SS-1);
  u16* p = buf + (size_t)row*EE + h*DD + 32;
  float e[48], o[48];
  #pragma unroll
  for (int c = 0; c < 12; c++){
    u16x8 v = *(const u16x8*)(p + c*8);
    #pragma unroll
    for (int j = 0; j < 4; j++){
      e[c*4 + j] = bf2f(v[2*j]);
      o[c*4 + j] = bf2f(v[2*j+1]);
    }
  }
  u16 ob[96];
  #pragma unroll
  for (int j = 0; j < 48; j++){
    float cs = cosb[s*48 + j], sn = sinb[s*48 + j];
    ob[j]      = f2bf(e[j]*cs - o[j]*sn);
    ob[48 + j] = f2bf(o[j]*cs + e[j]*sn);
  }
  #pragma unroll
  for (int c = 0; c < 12; c++)
    *(u16x8*)(p + c*8) = *(const u16x8*)(ob + c*8);
}

// ---------------- GEMM 128^2 (m97 structure) for N=512 ----------------
__global__ __launch_bounds__(256) void gemm_bt(const u16* __restrict__ A,
    const u16* __restrict__ Bt, u16* __restrict__ C, int M, int N, int K){
  __shared__ u16 Al[128*32];
  __shared__ u16 Bl[128*32];
  const int tid = threadIdx.x;
  const int lane = tid & 63, w = tid >> 6;
  const int wr = w >> 1, wc = w & 1;
  const int l15 = lane & 15, l4 = lane >> 4;
  const int bm = blockIdx.y*128, bn = blockIdx.x*128;
  const int srow = tid >> 2;
  const int skc  = (tid & 3) * 8;
  const u16* ga = A  + (size_t)(bm + srow)*K + skc;
  const u16* gb = Bt + (size_t)(bn + srow)*K + skc;
  u16* la = Al + w*512;
  u16* lb = Bl + w*512;
  f32x4 acc[4][4] = {};
  for (int k0 = 0; k0 < K; k0 += 32){
    __syncthreads();
    g2l16(ga + k0,          la);
    g2l16(ga + 64*K + k0,   la + 2048);
    g2l16(gb + k0,          lb);
    g2l16(gb + 64*K + k0,   lb + 2048);
    __syncthreads();
    bf16x8 af[4], bfr[4];
    #pragma unroll
    for (int m = 0; m < 4; m++) af[m]  = ld8(Al + (wr*64 + m*16 + l15)*32 + l4*8);
    #pragma unroll
    for (int n = 0; n < 4; n++) bfr[n] = ld8(Bl + (wc*64 + n*16 + l15)*32 + l4*8);
    #pragma unroll
    for (int m = 0; m < 4; m++)
      #pragma unroll
      for (int n = 0; n < 4; n++)
        acc[m][n] = __builtin_amdgcn_mfma_f32_16x16x32_bf16(af[m], bfr[n], acc[m][n], 0, 0, 0);
  }
  #pragma unroll
  for (int m = 0; m < 4; m++)
    #pragma unroll
    for (int n = 0; n < 4; n++)
      #pragma unroll
      for (int r = 0; r < 4; r++){
        int row = bm + wr*64 + m*16 + l4*4 + r;
        int col = bn + wc*64 + n*16 + l15;
        C[(size_t)row*N + col] = f2bf(acc[m][n][r]);
      }
}

// ---------------- GEMM 256^2, 8-phase double-buffered, counted vmcnt ----------------
#define AFR(buf, mf, ks) ld8(&AL[buf][wr][((mf)*16 + l15)*64 + ((((ks)*4 + l4) ^ r7) << 3)])
#define BFR(buf, nf, ks) ld8(&BL[buf][wc>>1][(((wc&1)*64 + (nf)*16 + l15))*64 + ((((ks)*4 + l4) ^ r7) << 3)])

#define STAGE_A(buf, h, kt) stage2(aRow, (h), (kt), K, &AL[buf][h][0], wj0)
#define STAGE_B(buf, h, kt) stage2(bRow, (h), (kt), K, &BL[buf][h][0], wj0)

__device__ __forceinline__ void stage2(const u16* rowbase, int h, int kt, int K,
                                       u16* lds, int wj0){
  const u16* g = rowbase + (size_t)h*128*K + kt*64;
  g2l16(g,               lds + wj0*512);
  g2l16(g + (size_t)8*K, lds + wj0*512 + 512);
}

#define PHASE(buf, q, LOADB, STAGE, VM) do{                                        \
  bf16x8 a00 = AFR(buf, 2*(q)  , 0);                                              \
  bf16x8 a01 = AFR(buf, 2*(q)  , 1);                                              \
  bf16x8 a10 = AFR(buf, 2*(q)+1, 0);                                              \
  bf16x8 a11 = AFR(buf, 2*(q)+1, 1);                                              \
  if (LOADB){                                                                      \
    _Pragma("unroll")                                                              \
    for (int nf = 0; nf < 4; nf++){ bq[nf][0]=BFR(buf,nf,0); bq[nf][1]=BFR(buf,nf,1); } \
  }                                                                                \
  STAGE;                                                                           \
  if (VM) VMC(4);                                                                  \
  BARRIER();                                                                       \
  __builtin_amdgcn_s_setprio(1);                                                   \
  _Pragma("unroll")                                                                \
  for (int nf = 0; nf < 4; nf++){                                                  \
    acc[2*(q)][nf]   = __builtin_amdgcn_mfma_f32_16x16x32_bf16(a00, bq[nf][0], acc[2*(q)][nf],0,0,0);   \
    acc[2*(q)+1][nf] = __builtin_amdgcn_mfma_f32_16x16x32_bf16(a10, bq[nf][0], acc[2*(q)+1][nf],0,0,0); \
  }                                                                                \
  _Pragma("unroll")                                                                \
  for (int nf = 0; nf < 4; nf++){                                                  \
    acc[2*(q)][nf]   = __builtin_amdgcn_mfma_f32_16x16x32_bf16(a01, bq[nf][1], acc[2*(q)][nf],0,0,0);   \
    acc[2*(q)+1][nf] = __builtin_amdgcn_mfma_f32_16x16x32_bf16(a11, bq[nf][1], acc[2*(q)+1][nf],0,0,0); \
  }                                                                                \
  __builtin_amdgcn_s_setprio(0);                                                   \
  BARRIER();                                                                       \
  __builtin_amdgcn_sched_barrier(0);                                               \
}while(0)

__global__ __launch_bounds__(512, 2) void gemm8(const u16* __restrict__ A,
    const u16* __restrict__ Bt, u16* __restrict__ C0, u16* __restrict__ C1,
    int K, int Nout, int nsplit, int vt){
  __shared__ u16 AL[2][2][128*64];
  __shared__ u16 BL[2][2][128*64];
  const int tid = threadIdx.x, lane = tid & 63, w = tid >> 6;
  const int wr = w >> 2, wc = w & 3;
  const int l15 = lane & 15, l4 = lane >> 4;
  const int r7 = l15 & 7;
  const int bm = blockIdx.y*256, bn = blockIdx.x*256;
  const int wj0 = w*2;
  const int cswz = (lane & 7) ^ (lane >> 3);
  const u16* aRow = A  + (size_t)(bm + wj0*8 + (lane>>3))*K + cswz*8;
  const u16* bRow = Bt + (size_t)(bn + wj0*8 + (lane>>3))*K + cswz*8;

  const int nkt = K >> 6;
  const int niter = nkt >> 1;

  STAGE_A(0, 0, 0); STAGE_A(0, 1, 0);
  STAGE_B(0, 0, 0); STAGE_B(0, 1, 0);
  STAGE_B(1, 0, 1); STAGE_B(1, 1, 1);
  VMC(4);
  BARRIER();

  f32x4 acc[8][4] = {};
  bf16x8 bq[4][2];

  for (int it = 0; it < niter; ++it){
    const int kto = 2*it + 1;
    int kt2 = 2*it + 2; if (kt2 >= nkt) kt2 -= nkt;
    int kt3 = 2*it + 3; if (kt3 >= nkt) kt3 -= nkt;
    PHASE(0, 0, 1, STAGE_A(1, 0, kto), 0);
    PHASE(0, 1, 0, STAGE_A(1, 1, kto), 0);
    PHASE(0, 2, 0, STAGE_B(0, 0, kt2), 0);
    PHASE(0, 3, 0, STAGE_B(0, 1, kt2), 1);
    PHASE(1, 0, 1, STAGE_A(0, 0, kt2), 0);
    PHASE(1, 1, 0, STAGE_A(0, 1, kt2), 0);
    PHASE(1, 2, 0, STAGE_B(1, 0, kt3), 0);
    PHASE(1, 3, 0, STAGE_B(1, 1, kt3), 1);
  }
  asm volatile("s_waitcnt vmcnt(0)" ::: "memory");

  if (vt && bn >= nsplit){
    // transposed store: C1 is vpT[(b*16 + head)*128 + d][1024 s]
    const int bcol = bn - nsplit;
    #pragma unroll
    for (int mf = 0; mf < 8; mf++)
      #pragma unroll
      for (int nf = 0; nf < 4; nf++){
        int row0 = bm + wr*128 + mf*16 + l4*4;
        int col  = bcol + wc*64 + nf*16 + l15;
        int bh = (row0 >> 10)*16 + (col >> 7);
        int d  = col & 127;
        int s  = row0 & 1023;
        u16x4 pk;
        #pragma unroll
        for (int r = 0; r < 4; r++) pk[r] = f2bf(acc[mf][nf][r]);
        *(u16x4*)(C1 + (((size_t)(bh*128 + d)) << 10) + s) = pk;
      }
  } else {
    u16* Cd = (bn < nsplit) ? C0 : C1;
    const int bcol = (bn < nsplit) ? bn : bn - nsplit;
    #pragma unroll
    for (int mf = 0; mf < 8; mf++)
      #pragma unroll
      for (int nf = 0; nf < 4; nf++)
        #pragma unroll
        for (int r = 0; r < 4; r++){
          int row = bm + wr*128 + mf*16 + l4*4 + r;
          int col = bcol + wc*64 + nf*16 + l15;
          Cd[(size_t)row*Nout + col] = f2bf(acc[mf][nf][r]);
        }
  }
}

// ---------------- Flash attention v3: g2l16 staging, counted vmcnt ----------------
// K staged row-major [64][128] with chunk^=(row&7) swizzle (pre-swizzled source);
// V staged from transposed global vpT as [128 d][64 kv] with same swizzle.
__global__ __launch_bounds__(512) void attn(const u16* __restrict__ qp,
                                            const u16* __restrict__ kp,
                                            const u16* __restrict__ vpT,
                                            float* __restrict__ out){
  __shared__ u16 Kl[2][64*128];   // 32768 B
  __shared__ u16 Vl[128*64];      // 16384 B
  __shared__ u16 Pl[8][16*72];    // 18432 B
  const int tid = threadIdx.x, lane = tid & 63, w = tid >> 6;
  const int l15 = lane & 15, l4 = lane >> 4;
  const int qt = 7 - blockIdx.y;
  const int bh = blockIdx.x;
  const int b = bh >> 4, h = bh & 15;
  const int qbase = qt*128;
  const int qmin = qbase + w*16;
  const float c = 0.12751920700948998f;   // (1/sqrt(128)) * log2(e)

  // staging lane geometry (source per-lane, dest wave-uniform)
  const int kR0 = w*8 + (l4 & 3) + ((lane>>4)==0 ? 0 : 0);  // see loop below
  // Q fragments
  const size_t rowq = (size_t)(b*SS + qmin + l15)*EE + h*DD;
  bf16x8 qf[4];
  #pragma unroll
  for (int kk = 0; kk < 4; kk++) qf[kk] = ld8(qp + rowq + kk*32 + l4*8);
  #pragma unroll
  for (int kk = 0; kk < 4; kk++) asm volatile("" : "+v"(qf[kk]));

  f32x4 ao[8] = {};
  float mi[4], li[4];
  #pragma unroll
  for (int r = 0; r < 4; r++){ mi[r] = -3e38f; li[r] = 0.0f; }

  const int ntiles = 2*qt + 2;

  // prologue: stage K(0) into Kl[0]
  #pragma unroll
  for (int q = 0; q < 2; q++){
    int r = w*8 + q*4 + (lane>>4);
    int p = lane & 15;
    g2l16(kp + (size_t)(b*SS + r)*EE + h*DD + ((p ^ (r&7))<<3),
          &Kl[0][0] + (w*128 + q*64)*8);
  }
  VMC(0);

  for (int t = 0; t < ntiles; t++){
    const int kv0 = t*64;
    const int buf = t & 1;
    // stage V(t) (issue FIRST so vmcnt(2) below waits it, not K(t+1))
    #pragma unroll
    for (int q = 0; q < 2; q++){
      int d = w*16 + q*8 + (lane>>3);
      int cc = lane & 7;
      g2l16(vpT + (size_t)(bh*DD + d)*SS + kv0 + ((cc ^ (d&7))<<3),
            &Vl[0] + (w*128 + q*64)*8);
    }
    if (t + 1 < ntiles){
      #pragma unroll
      for (int q = 0; q < 2; q++){
        int r = w*8 + q*4 + (lane>>4);
        int p = lane & 15;
        g2l16(kp + (size_t)(b*SS + kv0 + 64 + r)*EE + h*DD + ((p ^ (r&7))<<3),
              &Kl[buf^1][0] + (w*128 + q*64)*8);
      }
      VMC(4);                       // K(t) complete; V(t)+K(t+1) in flight
    } else {
      VMC(2);                       // K(t) complete; V(t) in flight
    }
    BARRIER();                      // K(t) visible

    const bool part = (kv0 <= qmin + 15);
    float pout[4][4];
    if (part){
      float sv[4][4];
      #pragma unroll
      for (int nt = 0; nt < 4; nt++){
        f32x4 sacc = {};
        #pragma unroll
        for (int kk = 0; kk < 4; kk++){
          bf16x8 kf = ld8(&Kl[buf][0] + (nt*16 + l15)*128 + (((kk*4 + l4) ^ (l15&7))<<3));
          sacc = __builtin_amdgcn_mfma_f32_16x16x32_bf16(qf[kk], kf, sacc, 0, 0, 0);
        }
        #pragma unroll
        for (int r = 0; r < 4; r++) sv[nt][r] = sacc[r];
      }
      if (kv0 + 63 > qmin){
        #pragma unroll
        for (int nt = 0; nt < 4; nt++)
          #pragma unroll
          for (int r = 0; r < 4; r++){
            int qg = qmin + l4*4 + r;
            int kg_ = kv0 + nt*16 + l15;
            if (kg_ > qg) sv[nt][r] = -3e38f;
          }
      }
      #pragma unroll
      for (int r = 0; r < 4; r++){
        float mx = fmaxf(fmaxf(sv[0][r], sv[1][r]), fmaxf(sv[2][r], sv[3][r]));
        #pragma unroll
        for (int off = 1; off < 16; off <<= 1) mx = fmaxf(mx, __shfl_xor(mx, off));
        float mnew = fmaxf(mi[r], mx);
        float mnc = mnew * c;
        float alpha = __builtin_amdgcn_exp2f(__builtin_fmaf(mi[r], c, -mnc));
        float rs = 0.0f;
        #pragma unroll
        for (int nt = 0; nt < 4; nt++){
          float pv = __builtin_amdgcn_exp2f(__builtin_fmaf(sv[nt][r], c, -mnc));
          pout[nt][r] = pv; rs += pv;
        }
        #pragma unroll
        for (int off = 1; off < 16; off <<= 1) rs += __shfl_xor(rs, off);
        li[r] = li[r]*alpha + rs;
        mi[r] = mnew;
        #pragma unroll
        for (int n8 = 0; n8 < 8; n8++) ao[n8][r] *= alpha;
      }
      #pragma unroll
      for (int nt = 0; nt < 4; nt++)
        #pragma unroll
        for (int r = 0; r < 4; r++)
          Pl[w][(l4*4 + r)*72 + nt*16 + l15] = f2bf(pout[nt][r]);
    }
    if (t + 1 < ntiles) VMC(2); else VMC(0);   // V(t) complete
    BARRIER();                                  // V visible
    if (part){
      #pragma unroll
      for (int kk = 0; kk < 2; kk++){
        bf16x8 pa = ld8(&Pl[w][l15*72 + kk*32 + l4*8]);
        #pragma unroll
        for (int n8 = 0; n8 < 8; n8++){
          bf16x8 vf = ld8(&Vl[0] + (n8*16 + l15)*64 + (((kk*4 + l4) ^ (l15&7))<<3));
          ao[n8] = __builtin_amdgcn_mfma_f32_16x16x32_bf16(pa, vf, ao[n8], 0, 0, 0);
        }
      }
    }
    BARRIER();                      // all reads of Kl[buf]/Vl done before next stages
  }

  #pragma unroll
  for (int r = 0; r < 4; r++){
    float inv = 1.0f / li[r];
    size_t orow = (size_t)(b*SS + qmin + l4*4 + r)*EE + h*DD;
    #pragma unroll
    for (int n8 = 0; n8 < 8; n8++)
      out[orow + n8*16 + l15] = ao[n8][r]*inv;
  }
}

// ---------------- launch ----------------
extern "C" void kernel_launch(void* const* d_in, const int* in_sizes, int n_in,
                              void* d_out, int out_size, void* d_ws, size_t ws_size,
                              hipStream_t stream){
  const float* x    = (const float*)d_in[0];
  const float* Wq   = (const float*)d_in[1];
  const float* Wkvd = (const float*)d_in[2];
  const float* Wku  = (const float*)d_in[3];
  const float* Wvu  = (const float*)d_in[4];
  float* out = (float*)d_out;
  char* ws = (char*)d_ws;

  u16*   xb    = (u16*)  (ws);                 // 33,554,432 B
  u16*   WqT   = (u16*)  (ws +  33554432);     //  8,388,608
  u16*   WkvdT = (u16*)  (ws +  41943040);     //  2,097,152
  u16*   WkuT  = (u16*)  (ws +  44040192);     //  2,097,152 (WvuT adjacent)
  u16*   WvuT  = (u16*)  (ws +  46137344);     //  2,097,152
  float* cosb  = (float*)(ws +  48234496);     //    196,608
  float* sinb  = (float*)(ws +  48431104);     //    196,608
  u16*   qp    = (u16*)  (ws +  48627712);     // 33,554,432
  u16*   ckv   = (u16*)  (ws +  82182144);     //  8,388,608
  u16*   kp    = (u16*)  (ws +  90570752);     // 33,554,432
  u16*   vpT   = (u16*)  (ws + 124125184);     // 33,554,432 (transposed: [bh*128+d][1024])

  cvt_f32_bf16<<<(BB*SS*EE)/(256*8), 256, 0, stream>>>(x, xb, BB*SS*EE);
  transposeW<<<dim3(EE/32,  EE/32), 256, 0, stream>>>(Wq,   WqT,   EE,  EE);
  transposeW<<<dim3(512/32, EE/32), 256, 0, stream>>>(Wkvd, WkvdT, EE,  512);
  transposeW<<<dim3(EE/32, 512/32), 256, 0, stream>>>(Wku,  WkuT,  512, EE);
  transposeW<<<dim3(EE/32, 512/32), 256, 0, stream>>>(Wvu,  WvuT,  512, EE);
  rope_tables<<<(SS*48 + 255)/256, 256, 0, stream>>>(cosb, sinb);

  // q = x @ Wq  (M=8192, N=2048, K=2048)
  gemm8<<<dim3(EE/256, (BB*SS)/256), 512, 0, stream>>>(xb, WqT, qp, qp, EE, EE, EE, 0);
  // c_kv = x @ Wkv_down (N=512)
  gemm_bt<<<dim3(512/128, (BB*SS)/128), 256, 0, stream>>>(xb, WkvdT, ckv, BB*SS, 512, EE);
  // fused k/v up-projection (N=4096, K=512); V half written transposed
  gemm8<<<dim3(4096/256, (BB*SS)/256), 512, 0, stream>>>(ckv, WkuT, kp, vpT, 512, EE, EE, 1);

  rope_apply<<<(BB*SS*HH)/256, 256, 0, stream>>>(qp, cosb, sinb);
  rope_apply<<<(BB*SS*HH)/256, 256, 0, stream>>>(kp, cosb, sinb);

  attn<<<dim3(BB*HH, SS/128), 512, 0, stream>>>(qp, kp, vpT, out);
}